// Round 2
// baseline (62.949 us; speedup 1.0000x reference)
//
#include <hip/hip_runtime.h>

// LiftingScheme == plain 3x3 same-padding conv2d (predict/update coeffs cancel
// exactly to w): out[n,o,i,j] = sum_{c,kh,kw} w[o,c,kh,kw]*x[n,c,i+kh-1,j+kw-1]
//
// Round-4: round-3 (16 waves/block) helped (74->62.4) but kernel is still
// ~20us vs a ~2us VALU wall. Suspects: (a) unroll-2 kept ~72 weights live ->
// SGPR overflow -> weights in VGPRs -> at the launch_bounds(1024,4) 128-VGPR
// cap -> scratch spills; (b) div-heavy serial staging + full lgkmcnt(0)
// drains with no prefetch distance. Changes:
//  1. Staging: wave-per-row map (rowid = p*16+wv, lane = column). No integer
//     division, 8 independent coalesced loads per lane all in flight, then 8
//     ds_writes. Straight-line, fully unrolled.
//  2. Main loop: rotation-prefetch (x window for cc+1 loads during cc's FMAs)
//     with only 36 weights live at a time -> weights stay in SGPRs
//     (v_fmac_f32 v,s,v), VGPR ~45 / SGPR ~60 by construction: no spill.
// Decomposition unchanged: 224 blocks x 16 waves = 4 o-quads x 4 C-chunks,
// LDS-tree reduction over C-partials reusing the x tile buffer.

namespace {
constexpr int Cc = 32, Hh = 56, Ww = 56, Oo = 64;

constexpr int RSTRIDE = 10;   // floats per lane slot in reduction scratch (8B-aligned, bank-spread)
constexpr int REGION  = 576;  // >= 56*RSTRIDE, per (cchunk,oq) partial region

__global__ __launch_bounds__(1024, 4)
void lifting_conv_kernel(const float* __restrict__ x,
                         const float* __restrict__ w,
                         float* __restrict__ out)
{
    // x tile: [C][4 padded rows][60 (58 used)] = 7680 floats = 30 KB.
    // Reused after the c-loop as reduction scratch: 12 regions * 576 = 6912 floats.
    __shared__ float xs[Cc * 4 * 60];

    const int tid  = threadIdx.x;
    const int og   = blockIdx.x;   // 0..3  -> o0 = 16*og
    const int ip   = blockIdx.y;   // 0..27 -> rows 2*ip, 2*ip+1
    const int n    = blockIdx.z;   // 0..1
    const int i0   = ip * 2;
    const int lane = tid & 63;
    const int wv   = tid >> 6;     // wave id 0..15

    // ---- stage x rows i0-1..i0+2 (zero-padded), cols -1..56 (zero-padded) ----
    // wave wv stages LDS rows {p*16 + wv : p=0..7}; lane = jj (column+1).
    {
        const int col = lane - 1;
        const bool cok = (lane < 58) && ((unsigned)col < (unsigned)Ww);
        float v[8];
        #pragma unroll
        for (int p = 0; p < 8; ++p) {
            const int rowid = p * 16 + wv;     // = c*4 + r, c = rowid>>2
            const int r = rowid & 3;
            const int h = i0 - 1 + r;
            v[p] = 0.0f;
            if (cok && (unsigned)h < (unsigned)Hh)
                v[p] = x[((n * Cc + (rowid >> 2)) * Hh + h) * Ww + col];
        }
        if (lane < 58) {
            #pragma unroll
            for (int p = 0; p < 8; ++p)
                xs[(p * 16 + wv) * 60 + lane] = v[p];
        }
    }
    __syncthreads();

    const int oq   = wv & 3;              // o-quad within the block's 16 o
    const int cch  = wv >> 2;             // c-chunk 0..3 (8 channels each)
    const bool act = lane < 56;           // 56 active lanes per wave
    const int lact = act ? lane : 0;      // inactive lanes compute harmlessly
    const int rsub = (lact >= 28) ? 1 : 0;
    const int cp   = lact - rsub * 28;    // column pair 0..27
    const int col0 = cp * 2;

    // wave-uniform bases -> scalar (SMEM) weight loads, zero LDS spent on weights
    const int o_base = __builtin_amdgcn_readfirstlane(og * 16 + oq * 4);
    const int cbeg   = __builtin_amdgcn_readfirstlane(cch * 8);
    const float* __restrict__ wb = w + ((size_t)o_base * Cc + cbeg) * 9;

    float acc[4][2];
    #pragma unroll
    for (int i = 0; i < 4; ++i) { acc[i][0] = 0.f; acc[i][1] = 0.f; }

    const float* xbase = &xs[cbeg * 240 + rsub * 60 + col0];

    // prefetch the cc=0 register window (3 rows x 4 cols, 6x ds_read_b64)
    float2 a0 = *(const float2*)(xbase);
    float2 a1 = *(const float2*)(xbase + 2);
    float2 b0 = *(const float2*)(xbase + 60);
    float2 b1 = *(const float2*)(xbase + 62);
    float2 d0 = *(const float2*)(xbase + 120);
    float2 d1 = *(const float2*)(xbase + 122);

    #pragma unroll 2
    for (int cc = 0; cc < 8; ++cc) {
        const float2 r0a = a0, r0b = a1,
                     r1a = b0, r1b = b1,
                     r2a = d0, r2b = d1;
        if (cc < 7) {   // prefetch cc+1 while cc's FMAs run
            const float* xn = xbase + (cc + 1) * 240;
            a0 = *(const float2*)(xn);
            a1 = *(const float2*)(xn + 2);
            b0 = *(const float2*)(xn + 60);
            b1 = *(const float2*)(xn + 62);
            d0 = *(const float2*)(xn + 120);
            d1 = *(const float2*)(xn + 122);
        }
        #pragma unroll
        for (int oo = 0; oo < 4; ++oo) {
            const float* wc = wb + (oo * Cc + cc) * 9;  // wave-uniform address
            const float w0 = wc[0], w1 = wc[1], w2 = wc[2],
                        w3 = wc[3], w4 = wc[4], w5 = wc[5],
                        w6 = wc[6], w7 = wc[7], w8 = wc[8];
            acc[oo][0] += w0 * r0a.x + w1 * r0a.y + w2 * r0b.x
                        + w3 * r1a.x + w4 * r1a.y + w5 * r1b.x
                        + w6 * r2a.x + w7 * r2a.y + w8 * r2b.x;
            acc[oo][1] += w0 * r0a.y + w1 * r0b.x + w2 * r0b.y
                        + w3 * r1a.y + w4 * r1b.x + w5 * r1b.y
                        + w6 * r2a.y + w7 * r2b.x + w8 * r2b.y;
        }
    }

    // ---- reduce the 4 C-chunk partials through LDS (xs is dead now) ----
    __syncthreads();   // all x reads done before xs is overwritten

    if (cch > 0 && act) {
        float* p = &xs[((cch - 1) * 4 + oq) * REGION + lane * RSTRIDE];
        #pragma unroll
        for (int oo = 0; oo < 4; ++oo)
            *(float2*)(p + oo * 2) = make_float2(acc[oo][0], acc[oo][1]);
    }
    __syncthreads();

    if (cch == 0 && act) {
        #pragma unroll
        for (int pi = 0; pi < 3; ++pi) {
            const float* p = &xs[(pi * 4 + oq) * REGION + lane * RSTRIDE];
            #pragma unroll
            for (int oo = 0; oo < 4; ++oo) {
                const float2 v = *(const float2*)(p + oo * 2);
                acc[oo][0] += v.x;
                acc[oo][1] += v.y;
            }
        }
        const int row = i0 + rsub;
        #pragma unroll
        for (int oo = 0; oo < 4; ++oo) {
            float2 v; v.x = acc[oo][0]; v.y = acc[oo][1];
            *(float2*)(out + ((size_t)(n * Oo + o_base + oo) * Hh + row) * Ww + col0) = v;
        }
    }
}
} // namespace

extern "C" void kernel_launch(void* const* d_in, const int* in_sizes, int n_in,
                              void* d_out, int out_size, void* d_ws, size_t ws_size,
                              hipStream_t stream)
{
    const float* x = (const float*)d_in[0];   // (2,32,56,56) fp32
    const float* w = (const float*)d_in[1];   // (64,32,3,3) fp32
    float* out = (float*)d_out;               // (2,64,56,56) fp32

    dim3 grid(4, 28, 2);  // (o-groups of 16, row-pairs, n) = 224 blocks
    lifting_conv_kernel<<<grid, 1024, 0, stream>>>(x, w, out);
}